// Round 1
// baseline (291.732 us; speedup 1.0000x reference)
//
#include <hip/hip_runtime.h>

// SnEncoder on MI355X. Exact decomposition: y1 = P1(i,j)+Q1(i,k)+R1(j,k)+A(i)+B(j)+C(k)
// (pair/single tensors from pre-combined W1 blocks); h1 means via sweeps; layer-2
// G = h1*W2[0:64] via bf16 MFMA recompute (twice: BN2 stats, h2 reductions).
// Workspace need: ~39.6M floats (~158MB? no: 9,895,936 floats = 39.6MB). Assumes ws_size >= 40MB.

typedef float f32x4 __attribute__((ext_vector_type(4)));
typedef __bf16 bfv8 __attribute__((ext_vector_type(8)));
typedef unsigned int u32x4v __attribute__((ext_vector_type(4)));

#define DEVI static __device__ __forceinline__

DEVI unsigned f2bfu(float f){
  unsigned u = __float_as_uint(f);
  return (u + 0x7fffu + ((u >> 16) & 1u)) >> 16;   // RNE f32->bf16 bits
}

// ---------------- workspace offsets (in floats) ----------------
#define O_WP    0
#define O_WQ    1024
#define O_WR    2048
#define O_WAV   3072
#define O_WBU   4096
#define O_WBV   5120
#define O_WCU   6144
#define O_WD    7168
#define O_U     8192
#define O_V     16384
#define O_GM    24576
#define O_AB    24832
#define O_BB    57600
#define O_CB    90368
#define O_SUM1  123136
#define O_SSQ1  123200
#define O_SC1   123264
#define O_SH1   123328
#define O_SUM2  123392
#define O_SSQ2  123456
#define O_SC2   123520
#define O_SH2   123584
#define O_SUMC  123648
#define O_SSQC  123712
#define O_D2    123776
#define O_D3    124800
#define O_S23H  125824
#define O_S13H  158592
#define O_S12H  191360
#define O_A2    224128
#define O_B2    256896
#define O_C2    289664
#define O_T23   322432
#define O_T13   355200
#define O_T12   387968
#define O_OUT1  420736
#define O_P1    458752
#define O_Q1    1507328
#define O_R1    2555904
#define O_S1S   3604480
#define O_S2S   4653056
#define O_S3S   5701632
#define O_P2    6750208
#define O_Q2    7798784
#define O_R2    8847360
#define WS_FLOATS 9895936

// ---------------- row/col means of x ----------------
__global__ __launch_bounds__(512) void k_means(const float* __restrict__ x, float* __restrict__ ws){
  int b = blockIdx.x; int t = threadIdx.x; int r = t >> 4, c = t & 15;
  __shared__ float ul[32][16];
  float au = 0.f, av = 0.f;
  for (int i = 0; i < 32; i++){
    au += x[((b*32+i)*32+r)*16+c];   // mean over first pair index -> u[b,r]
    av += x[((b*32+r)*32+i)*16+c];   // mean over second pair index -> v[b,r]
  }
  au *= (1.f/32.f); av *= (1.f/32.f);
  ws[O_U + (b*32+r)*16+c] = au;
  ws[O_V + (b*32+r)*16+c] = av;
  ul[r][c] = au;
  __syncthreads();
  if (t < 16){
    float g = 0.f;
    for (int r2 = 0; r2 < 32; r2++) g += ul[r2][t];
    ws[O_GM + b*16+t] = g * (1.f/32.f);
  }
}

// ---------------- combine W1 blocks ----------------
__global__ __launch_bounds__(64) void k_wcomb(const float* __restrict__ W1, float* __restrict__ ws){
  int d = threadIdx.x;
#define W1AT(tt,comp,cc) W1[(((tt)*48 + (comp)*16 + (cc))*64) + d]
  for (int c = 0; c < 16; c++){
    ws[O_WP  + c*64+d] = W1AT(0,0,c) + W1AT(3,0,c);
    ws[O_WQ  + c*64+d] = W1AT(0,1,c) + W1AT(2,1,c);
    ws[O_WR  + c*64+d] = W1AT(0,2,c) + W1AT(1,2,c);
    ws[O_WAV + c*64+d] = W1AT(2,0,c) + W1AT(3,1,c) + W1AT(4,0,c) + W1AT(4,1,c);
    ws[O_WBU + c*64+d] = W1AT(1,0,c) + W1AT(5,0,c);
    ws[O_WBV + c*64+d] = W1AT(3,2,c) + W1AT(5,2,c);
    ws[O_WCU + c*64+d] = W1AT(1,1,c) + W1AT(2,2,c) + W1AT(6,1,c) + W1AT(6,2,c);
    ws[O_WD  + c*64+d] = W1AT(4,2,c) + W1AT(5,1,c) + W1AT(6,0,c) + W1AT(7,0,c) + W1AT(7,1,c) + W1AT(7,2,c);
  }
#undef W1AT
}

// ---------------- pair tensors P1,Q1,R1 = x * {WP,WQ,WR} ----------------
__global__ __launch_bounds__(64) void k_pairs1(const float* __restrict__ x, float* __restrict__ ws){
  int bid = blockIdx.x;                  // (b,p,q) linear
  int t = threadIdx.x;
  __shared__ float xl[16];
  if (t < 16) xl[t] = x[bid*16 + t];
  __syncthreads();
  float aP = 0.f, aQ = 0.f, aR = 0.f;
  for (int c = 0; c < 16; c++){
    float xv = xl[c];
    aP += xv * ws[O_WP + c*64 + t];
    aQ += xv * ws[O_WQ + c*64 + t];
    aR += xv * ws[O_WR + c*64 + t];
  }
  int o = bid*64 + t;
  ws[O_P1 + o] = aP; ws[O_Q1 + o] = aQ; ws[O_R1 + o] = aR;
}

// ---------------- single-index tensors A,B,C (D folded into A) ----------------
__global__ __launch_bounds__(64) void k_singles1(const float* __restrict__ xn, const float* __restrict__ Wn1,
                                                 float* __restrict__ ws){
  int bid = blockIdx.x; int b = bid >> 5; int d = threadIdx.x;
  __shared__ float uv[16], vv[16], gml[16], xnl[8];
  if (d < 16){ uv[d] = ws[O_U + bid*16+d]; vv[d] = ws[O_V + bid*16+d]; gml[d] = ws[O_GM + b*16+d]; }
  if (d < 8) xnl[d] = xn[bid*8 + d];
  __syncthreads();
  float A = 0.f, Bv = 0.f, Cv = 0.f;
  for (int c = 0; c < 16; c++){
    A  += vv[c]*ws[O_WAV + c*64+d] + gml[c]*ws[O_WD + c*64+d];
    Bv += uv[c]*ws[O_WBU + c*64+d] + vv[c]*ws[O_WBV + c*64+d];
    Cv += uv[c]*ws[O_WCU + c*64+d];
  }
  for (int c = 0; c < 8; c++){
    A  += xnl[c]*Wn1[(c)*64 + d];
    Bv += xnl[c]*Wn1[(8 + c)*64 + d];
    Cv += xnl[c]*Wn1[(16 + c)*64 + d];
  }
  ws[O_AB + bid*64+d] = A; ws[O_BB + bid*64+d] = Bv; ws[O_CB + bid*64+d] = Cv;
}

// ---------------- BN1 stats sweep over y1 ----------------
__global__ __launch_bounds__(256) void k_bn1_stats(float* __restrict__ ws){
  int bid = blockIdx.x; int b = bid >> 5;
  int t = threadIdx.x;
  __shared__ float PB[2048], QC[2048], red[256];
  for (int idx = t; idx < 2048; idx += 256){
    int q = idx >> 6, d = idx & 63;
    PB[idx] = ws[O_P1 + (bid*32+q)*64+d] + ws[O_BB + (b*32+q)*64+d] + ws[O_AB + bid*64+d];
    QC[idx] = ws[O_Q1 + (bid*32+q)*64+d] + ws[O_CB + (b*32+q)*64+d];
  }
  __syncthreads();
  int w = t >> 6, d = t & 63;
  float s = 0.f, ss = 0.f;
  for (int jj = 0; jj < 8; jj++){
    int j = w*8 + jj;
    float pb = PB[j*64+d];
    const float* r1row = ws + O_R1 + ((b*32+j)*32)*64 + d;
    #pragma unroll
    for (int k = 0; k < 32; k++){
      float val = pb + QC[k*64+d] + r1row[k*64];
      s += val; ss += val*val;
    }
  }
  red[t] = s; __syncthreads();
  if (t < 64) atomicAdd(&ws[O_SUM1 + t], red[t]+red[t+64]+red[t+128]+red[t+192]);
  __syncthreads(); red[t] = ss; __syncthreads();
  if (t < 64) atomicAdd(&ws[O_SSQ1 + t], red[t]+red[t+64]+red[t+128]+red[t+192]);
}

// ---------------- BN finalize (shared) ----------------
__global__ __launch_bounds__(64) void k_bnfin(const float* __restrict__ g, const float* __restrict__ bb,
                                              float* __restrict__ ws, int osum, int ossq, int osc, int osh, float invN){
  int d = threadIdx.x;
  float mu = ws[osum+d]*invN;
  float var = ws[ossq+d]*invN - mu*mu;
  float sc = rsqrtf(var + 1e-5f) * g[d];
  ws[osc+d] = sc;
  ws[osh+d] = bb[d] - mu*sc;
}

// ---------------- h1 axis-sums, grouping (b,i): S2s, S3s ----------------
__global__ __launch_bounds__(256) void k_s2a(float* __restrict__ ws){
  int bid = blockIdx.x; int b = bid >> 5;
  int t = threadIdx.x;
  __shared__ float PB[2048], QC[2048];
  __shared__ float s2p[8192];
  for (int idx = t; idx < 2048; idx += 256){
    int q = idx >> 6, d = idx & 63;
    PB[idx] = ws[O_P1 + (bid*32+q)*64+d] + ws[O_BB + (b*32+q)*64+d] + ws[O_AB + bid*64+d];
    QC[idx] = ws[O_Q1 + (bid*32+q)*64+d] + ws[O_CB + (b*32+q)*64+d];
  }
  __syncthreads();
  int w = t >> 6, d = t & 63;
  float sc = ws[O_SC1+d], sh = ws[O_SH1+d];
  float acc2[32];
  #pragma unroll
  for (int k = 0; k < 32; k++) acc2[k] = 0.f;
  for (int jj = 0; jj < 8; jj++){
    int j = w*8 + jj;
    float pb = PB[j*64+d];
    const float* r1row = ws + O_R1 + ((b*32+j)*32)*64 + d;
    float a3 = 0.f;
    #pragma unroll
    for (int k = 0; k < 32; k++){
      float val = pb + QC[k*64+d] + r1row[k*64];
      float h = fmaxf(val*sc + sh, 0.f);
      a3 += h; acc2[k] += h;
    }
    ws[O_S3S + (bid*32+j)*64+d] = a3;     // sum over k
  }
  #pragma unroll
  for (int k = 0; k < 32; k++) s2p[(w*32+k)*64+d] = acc2[k];
  __syncthreads();
  for (int idx = t; idx < 2048; idx += 256){
    int k = idx >> 6, dd = idx & 63;
    ws[O_S2S + (bid*32+k)*64+dd] = s2p[k*64+dd] + s2p[2048+k*64+dd] + s2p[4096+k*64+dd] + s2p[6144+k*64+dd]; // sum over j
  }
}

// ---------------- h1 axis-sum, grouping (b,j): S1s ----------------
__global__ __launch_bounds__(256) void k_s2b(float* __restrict__ ws){
  int bid = blockIdx.x; int b = bid >> 5, j = bid & 31;
  int t = threadIdx.x;
  __shared__ float PA[2048], RC[2048];
  __shared__ float s1p[8192];
  for (int idx = t; idx < 2048; idx += 256){
    int q = idx >> 6, d = idx & 63;
    PA[idx] = ws[O_P1 + ((b*32+q)*32+j)*64+d] + ws[O_AB + (b*32+q)*64+d] + ws[O_BB + bid*64+d];
    RC[idx] = ws[O_R1 + (bid*32+q)*64+d] + ws[O_CB + (b*32+q)*64+d];
  }
  __syncthreads();
  int w = t >> 6, d = t & 63;
  float sc = ws[O_SC1+d], sh = ws[O_SH1+d];
  float acc1[32];
  #pragma unroll
  for (int k = 0; k < 32; k++) acc1[k] = 0.f;
  for (int ii = 0; ii < 8; ii++){
    int i = w*8 + ii;
    float pa = PA[i*64+d];
    const float* q1row = ws + O_Q1 + ((b*32+i)*32)*64 + d;
    #pragma unroll
    for (int k = 0; k < 32; k++){
      float val = pa + RC[k*64+d] + q1row[k*64];
      acc1[k] += fmaxf(val*sc + sh, 0.f);
    }
  }
  #pragma unroll
  for (int k = 0; k < 32; k++) s1p[(w*32+k)*64+d] = acc1[k];
  __syncthreads();
  for (int idx = t; idx < 2048; idx += 256){
    int k = idx >> 6, dd = idx & 63;
    ws[O_S1S + (bid*32+k)*64+dd] = s1p[k*64+dd] + s1p[2048+k*64+dd] + s1p[4096+k*64+dd] + s1p[6144+k*64+dd]; // sum over i
  }
}

// ---------------- layer-2 pair tensors ----------------
__global__ __launch_bounds__(64) void k_pairs2(const float* __restrict__ W2, float* __restrict__ ws){
  int bid = blockIdx.x; int t = threadIdx.x;
  __shared__ float r1[64], r2[64], r3[64];
  r1[t] = ws[O_S1S + bid*64 + t] * (1.f/32.f);
  r2[t] = ws[O_S2S + bid*64 + t] * (1.f/32.f);
  r3[t] = ws[O_S3S + bid*64 + t] * (1.f/32.f);
  __syncthreads();
  float aP = 0.f, aQ = 0.f, aR = 0.f;
  for (int c = 0; c < 64; c++){
    aP += r1[c] * W2[(64 + c)*64 + t];
    aQ += r2[c] * W2[(128 + c)*64 + t];
    aR += r3[c] * W2[(192 + c)*64 + t];
  }
  ws[O_P2 + bid*64+t] = aP;  // [b,j,k]
  ws[O_Q2 + bid*64+t] = aQ;  // [b,i,k]
  ws[O_R2 + bid*64+t] = aR;  // [b,i,j]
}

// ---------------- order-1 means of h1 ----------------
__global__ __launch_bounds__(64) void k_sred(float* __restrict__ ws){
  int bid = blockIdx.x; int b = bid >> 5, m = bid & 31; int d = threadIdx.x;
  float s23 = 0.f, s13 = 0.f, s12 = 0.f;
  for (int k = 0; k < 32; k++){
    s23 += ws[O_S2S + (bid*32+k)*64+d];
    s13 += ws[O_S1S + (bid*32+k)*64+d];
  }
  for (int j = 0; j < 32; j++) s12 += ws[O_S1S + ((b*32+j)*32+m)*64+d];
  ws[O_S23H + bid*64+d] = s23 * (1.f/1024.f);
  ws[O_S13H + bid*64+d] = s13 * (1.f/1024.f);
  ws[O_S12H + bid*64+d] = s12 * (1.f/1024.f);
}

__global__ __launch_bounds__(64) void k_d2(const float* __restrict__ W2, float* __restrict__ ws){
  int b = blockIdx.x; int t = threadIdx.x;
  __shared__ float l[64];
  float a = 0.f;
  for (int m = 0; m < 32; m++) a += ws[O_S23H + (b*32+m)*64+t];
  l[t] = a * (1.f/32.f);
  __syncthreads();
  float dv = 0.f;
  for (int c = 0; c < 64; c++) dv += l[c] * W2[(448 + c)*64 + t];
  ws[O_D2 + b*64+t] = dv;
}

__global__ __launch_bounds__(64) void k_ss2(const float* __restrict__ W2, float* __restrict__ ws){
  int bid = blockIdx.x; int b = bid >> 5; int t = threadIdx.x;
  __shared__ float r23[64], r13[64], r12[64];
  r23[t] = ws[O_S23H + bid*64+t];
  r13[t] = ws[O_S13H + bid*64+t];
  r12[t] = ws[O_S12H + bid*64+t];
  __syncthreads();
  float a = ws[O_D2 + b*64+t], bv = 0.f, cv = 0.f;
  for (int c = 0; c < 64; c++){
    a  += r23[c] * W2[(256 + c)*64 + t];
    bv += r13[c] * W2[(320 + c)*64 + t];
    cv += r12[c] * W2[(384 + c)*64 + t];
  }
  ws[O_A2 + bid*64+t] = a; ws[O_B2 + bid*64+t] = bv; ws[O_C2 + bid*64+t] = cv;
}

// ---------------- heavy pass: y2 = h1*W2[0:64] + low-order. PASS0: BN2 stats. PASS1: h2 reductions ----------------
template<int PASS>
__global__ __launch_bounds__(256) void k_y2(const float* __restrict__ W2, float* __restrict__ ws){
  int bid = blockIdx.x; int b = bid >> 5;
  int t = threadIdx.x; int w = t >> 6, lane = t & 63;
  __shared__ float PB1[2048], QC1[2048], RB2[2048], QC2[2048];
  __shared__ __align__(16) unsigned short h1t[2048];
  __shared__ float sc1l[64], sh1l[64];
  __shared__ float redA[128], redB[128];
  for (int idx = t; idx < 2048; idx += 256){
    int q = idx >> 6, d = idx & 63;
    PB1[idx] = ws[O_P1 + (bid*32+q)*64+d] + ws[O_BB + (b*32+q)*64+d] + ws[O_AB + bid*64+d];
    QC1[idx] = ws[O_Q1 + (bid*32+q)*64+d] + ws[O_CB + (b*32+q)*64+d];
    RB2[idx] = ws[O_R2 + (bid*32+q)*64+d] + ws[O_B2 + (b*32+q)*64+d] + ws[O_A2 + bid*64+d];
    QC2[idx] = ws[O_Q2 + (bid*32+q)*64+d] + ws[O_C2 + (b*32+q)*64+d];
  }
  if (t < 64){ sc1l[t] = ws[O_SC1+t]; sh1l[t] = ws[O_SH1+t]; }
  int mt = w & 1, ntb = (w >> 1) * 2;
  // B fragments: W2[0:64] columns, B[k=c][n=d]; lane holds B[ks*32+(lane>>4)*8+e][nt*16+(lane&15)]
  bfv8 bw[2][2];
  #pragma unroll
  for (int nt2 = 0; nt2 < 2; nt2++){
    #pragma unroll
    for (int ks = 0; ks < 2; ks++){
      int dcol = (ntb+nt2)*16 + (lane & 15);
      int c0 = ks*32 + (lane >> 4)*8;
      u32x4v pk;
      #pragma unroll
      for (int e2 = 0; e2 < 4; e2++){
        unsigned lo = f2bfu(W2[(c0 + 2*e2)*64 + dcol]);
        unsigned hi = f2bfu(W2[(c0 + 2*e2 + 1)*64 + dcol]);
        pk[e2] = lo | (hi << 16);
      }
      bw[nt2][ks] = __builtin_bit_cast(bfv8, pk);
    }
  }
  float sc2v[2] = {0.f,0.f}, sh2v[2] = {0.f,0.f};
  if (PASS == 1){
    #pragma unroll
    for (int nt2 = 0; nt2 < 2; nt2++){
      int dcol = (ntb+nt2)*16 + (lane & 15);
      sc2v[nt2] = ws[O_SC2+dcol]; sh2v[nt2] = ws[O_SH2+dcol];
    }
  }
  float ssum[2] = {0.f,0.f}, ssq[2] = {0.f,0.f};
  float t23a[2] = {0.f,0.f};
  float t12a[2][4] = {{0,0,0,0},{0,0,0,0}};
  __syncthreads();
  int kk = t >> 3, c0a = (t & 7) * 8;
  for (int j = 0; j < 32; j++){
    { // phase A: h1 tile [k][c] in bf16
      const float* rp = ws + O_R1 + ((b*32+j)*32 + kk)*64 + c0a;
      u32x4v pk;
      #pragma unroll
      for (int e2 = 0; e2 < 4; e2++){
        float v0 = PB1[j*64 + c0a + 2*e2]     + QC1[kk*64 + c0a + 2*e2]     + rp[2*e2];
        float v1 = PB1[j*64 + c0a + 2*e2 + 1] + QC1[kk*64 + c0a + 2*e2 + 1] + rp[2*e2+1];
        float h0 = fmaxf(v0*sc1l[c0a+2*e2]   + sh1l[c0a+2*e2],   0.f);
        float h1v = fmaxf(v1*sc1l[c0a+2*e2+1] + sh1l[c0a+2*e2+1], 0.f);
        pk[e2] = f2bfu(h0) | (f2bfu(h1v) << 16);
      }
      *reinterpret_cast<u32x4v*>(&h1t[kk*64 + c0a]) = pk;
    }
    __syncthreads();
    // phase B: MFMA 16x16x32, A row = lane&15, kchunk = (lane>>4)*8
    bfv8 a0 = __builtin_bit_cast(bfv8, *reinterpret_cast<const u32x4v*>(&h1t[(mt*16 + (lane&15))*64 + (lane>>4)*8]));
    bfv8 a1 = __builtin_bit_cast(bfv8, *reinterpret_cast<const u32x4v*>(&h1t[(mt*16 + (lane&15))*64 + 32 + (lane>>4)*8]));
    #pragma unroll
    for (int nt2 = 0; nt2 < 2; nt2++){
      f32x4 acc = {0.f,0.f,0.f,0.f};
      acc = __builtin_amdgcn_mfma_f32_16x16x32_bf16(a0, bw[nt2][0], acc, 0, 0, 0);
      acc = __builtin_amdgcn_mfma_f32_16x16x32_bf16(a1, bw[nt2][1], acc, 0, 0, 0);
      int dcol = (ntb+nt2)*16 + (lane & 15);
      float rb = RB2[j*64 + dcol];
      float t13j = 0.f;
      #pragma unroll
      for (int r = 0; r < 4; r++){
        int kl = mt*16 + (lane >> 4)*4 + r;   // C/D: col=lane&15, row=(lane>>4)*4+r (m89-verified)
        float val = acc[r] + rb + QC2[kl*64 + dcol] + ws[O_P2 + ((b*32+j)*32 + kl)*64 + dcol];
        if (PASS == 0){ ssum[nt2] += val; ssq[nt2] += val*val; }
        else {
          float h2 = fmaxf(val*sc2v[nt2] + sh2v[nt2], 0.f);
          t23a[nt2] += h2; t13j += h2; t12a[nt2][r] += h2;
        }
      }
      if (PASS == 1){
        t13j += __shfl_xor(t13j, 16); t13j += __shfl_xor(t13j, 32);
        if ((lane >> 4) == 0) atomicAdd(&ws[O_T13 + (b*32+j)*64 + dcol], t13j);
      }
    }
    __syncthreads();
  }
  if (PASS == 0){
    #pragma unroll
    for (int nt2 = 0; nt2 < 2; nt2++){
      float v = ssum[nt2]; v += __shfl_xor(v,16); v += __shfl_xor(v,32);
      float q = ssq[nt2];  q += __shfl_xor(q,16); q += __shfl_xor(q,32);
      if (lane < 16){ redA[(w*2+nt2)*16 + lane] = v; redB[(w*2+nt2)*16 + lane] = q; }
    }
    __syncthreads();
    if (t < 64){
      int nt = t >> 4, d15 = t & 15, w0 = (nt >> 1)*2, n2 = nt & 1;
      atomicAdd(&ws[O_SUM2 + t], redA[(w0*2+n2)*16+d15] + redA[((w0+1)*2+n2)*16+d15]);
      atomicAdd(&ws[O_SSQ2 + t], redB[(w0*2+n2)*16+d15] + redB[((w0+1)*2+n2)*16+d15]);
    }
  } else {
    #pragma unroll
    for (int nt2 = 0; nt2 < 2; nt2++){
      float v = t23a[nt2]; v += __shfl_xor(v,16); v += __shfl_xor(v,32);
      if (lane < 16) redA[(w*2+nt2)*16 + lane] = v;
    }
    __syncthreads();
    if (t < 64){
      int nt = t >> 4, d15 = t & 15, w0 = (nt >> 1)*2, n2 = nt & 1;
      ws[O_T23 + bid*64 + t] = redA[(w0*2+n2)*16+d15] + redA[((w0+1)*2+n2)*16+d15];
    }
    #pragma unroll
    for (int nt2 = 0; nt2 < 2; nt2++){
      int dcol = (ntb+nt2)*16 + (lane & 15);
      #pragma unroll
      for (int r = 0; r < 4; r++){
        int kl = mt*16 + (lane >> 4)*4 + r;
        atomicAdd(&ws[O_T12 + (b*32+kl)*64 + dcol], t12a[nt2][r]);
      }
    }
  }
}

// ---------------- final head ----------------
__global__ __launch_bounds__(64) void k_final_d3(const float* __restrict__ Wc, float* __restrict__ ws){
  int b = blockIdx.x; int t = threadIdx.x;
  __shared__ float l[64];
  float a = 0.f;
  for (int m = 0; m < 32; m++) a += ws[O_T23 + (b*32+m)*64 + t];
  l[t] = a * (1.f/32768.f);
  __syncthreads();
  float dv = 0.f;
  for (int c = 0; c < 64; c++) dv += l[c] * Wc[(192 + c)*64 + t];
  ws[O_D3 + b*64 + t] = dv;
}

__global__ __launch_bounds__(64) void k_final_out1(const float* __restrict__ Wc, float* __restrict__ ws){
  int bid = blockIdx.x; int b = bid >> 5; int t = threadIdx.x;
  __shared__ float r23[64], r13[64], r12[64];
  r23[t] = ws[O_T23 + bid*64+t] * (1.f/1024.f);
  r13[t] = ws[O_T13 + bid*64+t] * (1.f/1024.f);
  r12[t] = ws[O_T12 + bid*64+t] * (1.f/1024.f);
  __syncthreads();
  float o = ws[O_D3 + b*64 + t];
  for (int c = 0; c < 64; c++){
    o += r23[c]*Wc[c*64+t] + r13[c]*Wc[(64+c)*64+t] + r12[c]*Wc[(128+c)*64+t];
  }
  ws[O_OUT1 + bid*64+t] = o;
  atomicAdd(&ws[O_SUMC + t], o);
  atomicAdd(&ws[O_SSQC + t], o*o);
}

__global__ __launch_bounds__(64) void k_final_bn(const float* __restrict__ gc, const float* __restrict__ bc,
                                                 const float* __restrict__ ws, float* __restrict__ out){
  int bid = blockIdx.x; int t = threadIdx.x;
  float mu = ws[O_SUMC+t] * (1.f/512.f);
  float var = ws[O_SSQC+t] * (1.f/512.f) - mu*mu;
  float rs = rsqrtf(var + 1e-5f);
  out[bid*64 + t] = (ws[O_OUT1 + bid*64+t] - mu) * rs * gc[t] + bc[t];
}

extern "C" void kernel_launch(void* const* d_in, const int* in_sizes, int n_in,
                              void* d_out, int out_size, void* d_ws, size_t ws_size,
                              hipStream_t stream) {
  const float* x   = (const float*)d_in[0];
  const float* xn  = (const float*)d_in[1];
  const float* W1  = (const float*)d_in[2];
  const float* Wn1 = (const float*)d_in[3];
  const float* g1  = (const float*)d_in[4];
  const float* b1  = (const float*)d_in[5];
  const float* W2  = (const float*)d_in[6];
  const float* g2  = (const float*)d_in[7];
  const float* b2p = (const float*)d_in[8];
  const float* Wc  = (const float*)d_in[9];
  const float* gc  = (const float*)d_in[10];
  const float* bc  = (const float*)d_in[11];
  float* out = (float*)d_out;
  float* ws  = (float*)d_ws;
  (void)in_sizes; (void)n_in; (void)out_size; (void)ws_size; // needs ws_size >= 39.6MB

  // zero atomic accumulation targets
  hipMemsetAsync(ws + O_SUM1, 0, 128*4, stream);
  hipMemsetAsync(ws + O_SUM2, 0, 128*4, stream);
  hipMemsetAsync(ws + O_SUMC, 0, 128*4, stream);
  hipMemsetAsync(ws + O_T13,  0, 65536*4, stream);  // T13 + T12 contiguous

  k_means   <<<16,    512, 0, stream>>>(x, ws);
  k_wcomb   <<<1,     64,  0, stream>>>(W1, ws);
  k_pairs1  <<<16384, 64,  0, stream>>>(x, ws);
  k_singles1<<<512,   64,  0, stream>>>(xn, Wn1, ws);
  k_bn1_stats<<<512,  256, 0, stream>>>(ws);
  k_bnfin   <<<1,     64,  0, stream>>>(g1, b1, ws, O_SUM1, O_SSQ1, O_SC1, O_SH1, 1.f/524288.f);
  k_s2a     <<<512,   256, 0, stream>>>(ws);
  k_s2b     <<<512,   256, 0, stream>>>(ws);
  k_pairs2  <<<16384, 64,  0, stream>>>(W2, ws);
  k_sred    <<<512,   64,  0, stream>>>(ws);
  k_d2      <<<16,    64,  0, stream>>>(W2, ws);
  k_ss2     <<<512,   64,  0, stream>>>(W2, ws);
  k_y2<0>   <<<512,   256, 0, stream>>>(W2, ws);
  k_bnfin   <<<1,     64,  0, stream>>>(g2, b2p, ws, O_SUM2, O_SSQ2, O_SC2, O_SH2, 1.f/524288.f);
  k_y2<1>   <<<512,   256, 0, stream>>>(W2, ws);
  k_final_d3<<<16,    64,  0, stream>>>(Wc, ws);
  k_final_out1<<<512, 64,  0, stream>>>(Wc, ws);
  k_final_bn<<<512,   64,  0, stream>>>(gc, bc, ws, out);
}

// Round 2
// 276.260 us; speedup vs baseline: 1.0560x; 1.0560x over previous
//
#include <hip/hip_runtime.h>

// SnEncoder on MI355X, round 2.
// y1 = P1(i,j)+Q1(i,k)+R1(j,k)+A(i)+B(j)+C(k)  (exact decomposition of snconv3 on
// broadcast-structured input). BN1 stats computed in closed form from the pair/single
// tensors (no n^3 sweep). h1 = relu(bn1(y1)) materialized once as bf16 (67MB in ws);
// S1S via lean reduction; y2 passes read h1 fragments straight from global (no LDS
// staging, no barriers in the j-loop).  Needs ws_size >= ~107MB.

typedef float f32x4 __attribute__((ext_vector_type(4)));
typedef __bf16 bfv8 __attribute__((ext_vector_type(8)));
typedef unsigned int u32x4v __attribute__((ext_vector_type(4)));
typedef unsigned short u16x8 __attribute__((ext_vector_type(8)));

#define DEVI static __device__ __forceinline__

DEVI unsigned f2bfu(float f){
  unsigned u = __float_as_uint(f);
  return (u + 0x7fffu + ((u >> 16) & 1u)) >> 16;   // RNE f32->bf16 bits
}
DEVI float bf2f(unsigned short u){
  return __uint_as_float(((unsigned)u) << 16);
}

// ---------------- workspace offsets (in floats) ----------------
#define O_WP    0
#define O_WQ    1024
#define O_WR    2048
#define O_WAV   3072
#define O_WBU   4096
#define O_WBV   5120
#define O_WCU   6144
#define O_WD    7168
#define O_U     8192
#define O_V     16384
#define O_GM    24576
#define O_AB    24832
#define O_BB    57600
#define O_CB    90368
#define O_SUM1  123136
#define O_SSQ1  123200
#define O_SC1   123264
#define O_SH1   123328
#define O_SUM2  123392
#define O_SSQ2  123456
#define O_SC2   123520
#define O_SH2   123584
#define O_SUMC  123648
#define O_SSQC  123712
#define O_D2    123776
#define O_D3    124800
#define O_S23H  125824
#define O_S13H  158592
#define O_S12H  191360
#define O_A2    224128
#define O_B2    256896
#define O_C2    289664
#define O_T23   322432
#define O_T13   355200
#define O_T12   387968
#define O_OUT1  420736
#define O_P1    458752
#define O_Q1    1507328
#define O_R1    2555904
#define O_S1S   3604480
#define O_S2S   4653056
#define O_S3S   5701632
#define O_P2    6750208
#define O_Q2    7798784
#define O_R2    8847360
#define O_H1    9895936
// H1: 33,554,432 bf16 = 16,777,216 float slots -> ends at 26,673,152
#define O_BN1P  26673152
// BN1P: 7*1024 = 7168 floats -> total 26,680,320 floats (= ~106.7 MB)

// QC2 LDS bank swizzle: spread the 4 kl-groups (kl>>2 parity) over both bank halves
#define QIDX(k,d) ((k)*64 + ((d) ^ ((((k)>>2)&1)<<4)))

// ---------------- row/col means of x ----------------
__global__ __launch_bounds__(512) void k_means(const float* __restrict__ x, float* __restrict__ ws){
  int b = blockIdx.x; int t = threadIdx.x; int r = t >> 4, c = t & 15;
  __shared__ float ul[32][16];
  float au = 0.f, av = 0.f;
  for (int i = 0; i < 32; i++){
    au += x[((b*32+i)*32+r)*16+c];   // mean over first pair index -> u[b,r]
    av += x[((b*32+r)*32+i)*16+c];   // mean over second pair index -> v[b,r]
  }
  au *= (1.f/32.f); av *= (1.f/32.f);
  ws[O_U + (b*32+r)*16+c] = au;
  ws[O_V + (b*32+r)*16+c] = av;
  ul[r][c] = au;
  __syncthreads();
  if (t < 16){
    float g = 0.f;
    for (int r2 = 0; r2 < 32; r2++) g += ul[r2][t];
    ws[O_GM + b*16+t] = g * (1.f/32.f);
  }
}

// ---------------- combine W1 blocks ----------------
__global__ __launch_bounds__(64) void k_wcomb(const float* __restrict__ W1, float* __restrict__ ws){
  int d = threadIdx.x;
#define W1AT(tt,comp,cc) W1[(((tt)*48 + (comp)*16 + (cc))*64) + d]
  for (int c = 0; c < 16; c++){
    ws[O_WP  + c*64+d] = W1AT(0,0,c) + W1AT(3,0,c);
    ws[O_WQ  + c*64+d] = W1AT(0,1,c) + W1AT(2,1,c);
    ws[O_WR  + c*64+d] = W1AT(0,2,c) + W1AT(1,2,c);
    ws[O_WAV + c*64+d] = W1AT(2,0,c) + W1AT(3,1,c) + W1AT(4,0,c) + W1AT(4,1,c);
    ws[O_WBU + c*64+d] = W1AT(1,0,c) + W1AT(5,0,c);
    ws[O_WBV + c*64+d] = W1AT(3,2,c) + W1AT(5,2,c);
    ws[O_WCU + c*64+d] = W1AT(1,1,c) + W1AT(2,2,c) + W1AT(6,1,c) + W1AT(6,2,c);
    ws[O_WD  + c*64+d] = W1AT(4,2,c) + W1AT(5,1,c) + W1AT(6,0,c) + W1AT(7,0,c) + W1AT(7,1,c) + W1AT(7,2,c);
  }
#undef W1AT
}

// ---------------- pair tensors P1,Q1,R1 = x * {WP,WQ,WR} ----------------
__global__ __launch_bounds__(64) void k_pairs1(const float* __restrict__ x, float* __restrict__ ws){
  int bid = blockIdx.x;                  // (b,p,q) linear
  int t = threadIdx.x;
  __shared__ float xl[16];
  if (t < 16) xl[t] = x[bid*16 + t];
  __syncthreads();
  float aP = 0.f, aQ = 0.f, aR = 0.f;
  for (int c = 0; c < 16; c++){
    float xv = xl[c];
    aP += xv * ws[O_WP + c*64 + t];
    aQ += xv * ws[O_WQ + c*64 + t];
    aR += xv * ws[O_WR + c*64 + t];
  }
  int o = bid*64 + t;
  ws[O_P1 + o] = aP; ws[O_Q1 + o] = aQ; ws[O_R1 + o] = aR;
}

// ---------------- single-index tensors A,B,C (D folded into A) ----------------
__global__ __launch_bounds__(64) void k_singles1(const float* __restrict__ xn, const float* __restrict__ Wn1,
                                                 float* __restrict__ ws){
  int bid = blockIdx.x; int b = bid >> 5; int d = threadIdx.x;
  __shared__ float uv[16], vv[16], gml[16], xnl[8];
  if (d < 16){ uv[d] = ws[O_U + bid*16+d]; vv[d] = ws[O_V + bid*16+d]; gml[d] = ws[O_GM + b*16+d]; }
  if (d < 8) xnl[d] = xn[bid*8 + d];
  __syncthreads();
  float A = 0.f, Bv = 0.f, Cv = 0.f;
  for (int c = 0; c < 16; c++){
    A  += vv[c]*ws[O_WAV + c*64+d] + gml[c]*ws[O_WD + c*64+d];
    Bv += uv[c]*ws[O_WBU + c*64+d] + vv[c]*ws[O_WBV + c*64+d];
    Cv += uv[c]*ws[O_WCU + c*64+d];
  }
  for (int c = 0; c < 8; c++){
    A  += xnl[c]*Wn1[(c)*64 + d];
    Bv += xnl[c]*Wn1[(8 + c)*64 + d];
    Cv += xnl[c]*Wn1[(16 + c)*64 + d];
  }
  ws[O_AB + bid*64+d] = A; ws[O_BB + bid*64+d] = Bv; ws[O_CB + bid*64+d] = Cv;
}

// ---------------- BN1 stats, closed form, stage 1 ----------------
// Distributable partials per (b, m-index): squares, same-index cross terms, row sums.
__global__ __launch_bounds__(256) void k_bn1a(float* __restrict__ ws){
  int blk = blockIdx.x; int b = blk >> 3, ms = blk & 7;
  int t = threadIdx.x; int w = t >> 6, d = t & 63;
  int m = ms*4 + w;
  const float* P1 = ws + O_P1 + b*65536;
  const float* Q1 = ws + O_Q1 + b*65536;
  const float* R1 = ws + O_R1 + b*65536;
  float pR=0.f,pC=0.f,qR=0.f,qC=0.f,rR=0.f,rC=0.f,s2=0.f;
  for (int u = 0; u < 32; u++){
    float vp = P1[(m*32+u)*64+d];  pR += vp; s2 += vp*vp;
    float vq = Q1[(m*32+u)*64+d];  qR += vq; s2 += vq*vq;
    float vr = R1[(m*32+u)*64+d];  rR += vr; s2 += vr*vr;
    pC += P1[(u*32+m)*64+d];
    qC += Q1[(u*32+m)*64+d];
    rC += R1[(u*32+m)*64+d];
  }
  float a  = ws[O_AB + (b*32+m)*64+d];
  float bv = ws[O_BB + (b*32+m)*64+d];
  float cv = ws[O_CB + (b*32+m)*64+d];
  float sabc2 = a*a + bv*bv + cv*cv;
  float cidx = pR*qR + pC*rR + qC*rC;                       // pair-pair same-index
  float cps  = pR*a + pC*bv + qR*a + qC*cv + rR*bv + rC*cv; // pair-single same-index
  __shared__ float red[7][4][64];
  red[0][w][d]=s2; red[1][w][d]=sabc2; red[2][w][d]=cidx; red[3][w][d]=cps;
  red[4][w][d]=pR; red[5][w][d]=qR; red[6][w][d]=rR;
  __syncthreads();
  if (t < 64){
    #pragma unroll
    for (int q = 0; q < 7; q++){
      float v = red[q][0][t]+red[q][1][t]+red[q][2][t]+red[q][3][t];
      atomicAdd(&ws[O_BN1P + q*1024 + b*64 + t], v);
    }
  }
}

// ---------------- BN1 stats, stage 2: combine with full-sum products ----------------
__global__ __launch_bounds__(64) void k_bn1b(float* __restrict__ ws){
  int b = blockIdx.x; int d = threadIdx.x;
  float Sa=0.f, Sb=0.f, Sc=0.f;
  for (int i = 0; i < 32; i++){
    Sa += ws[O_AB + (b*32+i)*64+d];
    Sb += ws[O_BB + (b*32+i)*64+d];
    Sc += ws[O_CB + (b*32+i)*64+d];
  }
  float s2   = ws[O_BN1P + 0*1024 + b*64+d];
  float sab2 = ws[O_BN1P + 1*1024 + b*64+d];
  float cidx = ws[O_BN1P + 2*1024 + b*64+d];
  float cps  = ws[O_BN1P + 3*1024 + b*64+d];
  float Sp   = ws[O_BN1P + 4*1024 + b*64+d];
  float Sq   = ws[O_BN1P + 5*1024 + b*64+d];
  float Sr   = ws[O_BN1P + 6*1024 + b*64+d];
  const float n = 32.f, n2 = 1024.f;
  float SUMb = n*(Sp+Sq+Sr) + n2*(Sa+Sb+Sc);
  float SSQb = n*s2 + n2*sab2 + 2.f*cidx + 2.f*n*cps
             + 2.f*(Sp*Sc + Sq*Sb + Sr*Sa)
             + 2.f*n*(Sa*Sb + Sa*Sc + Sb*Sc);
  atomicAdd(&ws[O_SUM1 + d], SUMb);
  atomicAdd(&ws[O_SSQ1 + d], SSQb);
}

// ---------------- BN finalize (shared) ----------------
__global__ __launch_bounds__(64) void k_bnfin(const float* __restrict__ g, const float* __restrict__ bb,
                                              float* __restrict__ ws, int osum, int ossq, int osc, int osh, float invN){
  int d = threadIdx.x;
  float mu = ws[osum+d]*invN;
  float var = ws[ossq+d]*invN - mu*mu;
  float sc = rsqrtf(var + 1e-5f) * g[d];
  ws[osc+d] = sc;
  ws[osh+d] = bb[d] - mu*sc;
}

// ---------------- sweep: h1 -> bf16 H1, S2S (sum_j), S3S (sum_k) ----------------
__global__ __launch_bounds__(256) void k_sweep1(float* __restrict__ ws, unsigned short* __restrict__ H1){
  int bid = blockIdx.x; int b = bid >> 5;
  int t = threadIdx.x;
  __shared__ float PB[2048], QC[2048];
  __shared__ float s2p[8192];
  for (int idx = t; idx < 2048; idx += 256){
    int q = idx >> 6, d = idx & 63;
    float sc = ws[O_SC1+d];
    PB[idx] = (ws[O_P1 + (bid*32+q)*64+d] + ws[O_BB + (b*32+q)*64+d] + ws[O_AB + bid*64+d]) * sc;
    QC[idx] = (ws[O_Q1 + (bid*32+q)*64+d] + ws[O_CB + (b*32+q)*64+d]) * sc + ws[O_SH1+d];
  }
  __syncthreads();
  int w = t >> 6, d = t & 63;
  float scd = ws[O_SC1+d];
  float acc2[32];
  #pragma unroll
  for (int k = 0; k < 32; k++) acc2[k] = 0.f;
  for (int jj = 0; jj < 8; jj++){
    int j = w*8 + jj;
    float pb = PB[j*64+d];
    const float* r1row = ws + O_R1 + ((b*32+j)*32)*64 + d;
    unsigned short* hrow = H1 + (((size_t)bid*32+j)*32)*64 + d;
    float a3 = 0.f;
    #pragma unroll
    for (int k = 0; k < 32; k++){
      float h = fmaxf(fmaf(r1row[k*64], scd, pb + QC[k*64+d]), 0.f);
      a3 += h; acc2[k] += h;
      hrow[k*64] = (unsigned short)f2bfu(h);
    }
    ws[O_S3S + (bid*32+j)*64+d] = a3;     // sum over k
  }
  #pragma unroll
  for (int k = 0; k < 32; k++) s2p[(w*32+k)*64+d] = acc2[k];
  __syncthreads();
  for (int idx = t; idx < 2048; idx += 256){
    int k = idx >> 6, dd = idx & 63;
    ws[O_S2S + (bid*32+k)*64+dd] = s2p[k*64+dd] + s2p[2048+k*64+dd] + s2p[4096+k*64+dd] + s2p[6144+k*64+dd]; // sum over j
  }
}

// ---------------- S1S = sum_i h1 (lean reduction over stored H1) ----------------
__global__ __launch_bounds__(256) void k_hred(float* __restrict__ ws, const unsigned short* __restrict__ H1){
  int bid = blockIdx.x; int b = bid >> 5, j = bid & 31;
  int t = threadIdx.x;
  float acc[8];
  #pragma unroll
  for (int e = 0; e < 8; e++) acc[e] = 0.f;
  for (int i = 0; i < 32; i++){
    const unsigned short* p = H1 + ((((size_t)b*32+i)*32+j)*32)*64 + t*8;
    u16x8 v = *reinterpret_cast<const u16x8*>(p);
    #pragma unroll
    for (int e = 0; e < 8; e++) acc[e] += bf2f(v[e]);
  }
  float* o = ws + O_S1S + ((size_t)bid*32)*64 + t*8;   // element t*8 = kk*64+c0
  #pragma unroll
  for (int e = 0; e < 8; e++) o[e] = acc[e];
}

// ---------------- layer-2 pair tensors ----------------
__global__ __launch_bounds__(64) void k_pairs2(const float* __restrict__ W2, float* __restrict__ ws){
  int bid = blockIdx.x; int t = threadIdx.x;
  __shared__ float r1[64], r2[64], r3[64];
  r1[t] = ws[O_S1S + bid*64 + t] * (1.f/32.f);
  r2[t] = ws[O_S2S + bid*64 + t] * (1.f/32.f);
  r3[t] = ws[O_S3S + bid*64 + t] * (1.f/32.f);
  __syncthreads();
  float aP = 0.f, aQ = 0.f, aR = 0.f;
  for (int c = 0; c < 64; c++){
    aP += r1[c] * W2[(64 + c)*64 + t];
    aQ += r2[c] * W2[(128 + c)*64 + t];
    aR += r3[c] * W2[(192 + c)*64 + t];
  }
  ws[O_P2 + bid*64+t] = aP;  // [b,j,k]
  ws[O_Q2 + bid*64+t] = aQ;  // [b,i,k]
  ws[O_R2 + bid*64+t] = aR;  // [b,i,j]
}

// ---------------- order-1 means of h1 ----------------
__global__ __launch_bounds__(64) void k_sred(float* __restrict__ ws){
  int bid = blockIdx.x; int b = bid >> 5, m = bid & 31; int d = threadIdx.x;
  float s23 = 0.f, s13 = 0.f, s12 = 0.f;
  for (int k = 0; k < 32; k++){
    s23 += ws[O_S2S + (bid*32+k)*64+d];
    s13 += ws[O_S1S + (bid*32+k)*64+d];
  }
  for (int j = 0; j < 32; j++) s12 += ws[O_S1S + ((b*32+j)*32+m)*64+d];
  ws[O_S23H + bid*64+d] = s23 * (1.f/1024.f);
  ws[O_S13H + bid*64+d] = s13 * (1.f/1024.f);
  ws[O_S12H + bid*64+d] = s12 * (1.f/1024.f);
}

__global__ __launch_bounds__(64) void k_d2(const float* __restrict__ W2, float* __restrict__ ws){
  int b = blockIdx.x; int t = threadIdx.x;
  __shared__ float l[64];
  float a = 0.f;
  for (int m = 0; m < 32; m++) a += ws[O_S23H + (b*32+m)*64+t];
  l[t] = a * (1.f/32.f);
  __syncthreads();
  float dv = 0.f;
  for (int c = 0; c < 64; c++) dv += l[c] * W2[(448 + c)*64 + t];
  ws[O_D2 + b*64+t] = dv;
}

__global__ __launch_bounds__(64) void k_ss2(const float* __restrict__ W2, float* __restrict__ ws){
  int bid = blockIdx.x; int b = bid >> 5; int t = threadIdx.x;
  __shared__ float r23[64], r13[64], r12[64];
  r23[t] = ws[O_S23H + bid*64+t];
  r13[t] = ws[O_S13H + bid*64+t];
  r12[t] = ws[O_S12H + bid*64+t];
  __syncthreads();
  float a = ws[O_D2 + b*64+t], bv = 0.f, cv = 0.f;
  for (int c = 0; c < 64; c++){
    a  += r23[c] * W2[(256 + c)*64 + t];
    bv += r13[c] * W2[(320 + c)*64 + t];
    cv += r12[c] * W2[(384 + c)*64 + t];
  }
  ws[O_A2 + bid*64+t] = a; ws[O_B2 + bid*64+t] = bv; ws[O_C2 + bid*64+t] = cv;
}

// ---------------- lean y2 passes: G = h1*W2[0:64] from stored bf16 H1 ----------------
// PASS0: BN2 sum/ssq.  PASS1: h2 reductions T23/T13/T12.
// Grid: 1024 blocks = (b,i) x jh; no barriers in the j-loop, A-frags loaded from global.
template<int PASS>
__global__ __launch_bounds__(256) void k_y2lean(const float* __restrict__ W2, float* __restrict__ ws,
                                                const unsigned short* __restrict__ H1){
  int blk = blockIdx.x;
  int bid = blk >> 1;              // (b,i)
  int b = bid >> 5;
  int jh = blk & 1;
  int t = threadIdx.x; int w = t >> 6, lane = t & 63;
  __shared__ float RB2[2048], QC2[2048];
  __shared__ float redA[128], redB[128];
  for (int idx = t; idx < 2048; idx += 256){
    int q = idx >> 6, d = idx & 63;
    RB2[idx] = ws[O_R2 + (bid*32+q)*64+d] + ws[O_B2 + (b*32+q)*64+d] + ws[O_A2 + bid*64+d];
    QC2[QIDX(q,d)] = ws[O_Q2 + (bid*32+q)*64+d] + ws[O_C2 + (b*32+q)*64+d];
  }
  int mt = w & 1, ntb = (w >> 1) * 2;
  // B fragments: W2[0:64] columns; lane holds B[ks*32+(lane>>4)*8+e][(ntb+nt2)*16+(lane&15)]
  bfv8 bw[2][2];
  #pragma unroll
  for (int nt2 = 0; nt2 < 2; nt2++){
    #pragma unroll
    for (int ks = 0; ks < 2; ks++){
      int dcol = (ntb+nt2)*16 + (lane & 15);
      int c0 = ks*32 + (lane >> 4)*8;
      u32x4v pk;
      #pragma unroll
      for (int e2 = 0; e2 < 4; e2++){
        unsigned lo = f2bfu(W2[(c0 + 2*e2)*64 + dcol]);
        unsigned hi = f2bfu(W2[(c0 + 2*e2 + 1)*64 + dcol]);
        pk[e2] = lo | (hi << 16);
      }
      bw[nt2][ks] = __builtin_bit_cast(bfv8, pk);
    }
  }
  float sc2v[2] = {0.f,0.f}, sh2v[2] = {0.f,0.f};
  if (PASS == 1){
    #pragma unroll
    for (int nt2 = 0; nt2 < 2; nt2++){
      int dcol = (ntb+nt2)*16 + (lane & 15);
      sc2v[nt2] = ws[O_SC2+dcol]; sh2v[nt2] = ws[O_SH2+dcol];
    }
  }
  float ssum[2] = {0.f,0.f}, ssq[2] = {0.f,0.f};
  float t23a[2] = {0.f,0.f};
  float t12a[2][4] = {{0,0,0,0},{0,0,0,0}};
  __syncthreads();
  // per-lane A-fragment base: row = mt*16+(lane&15) (k index), chunk (lane>>4)*8 (channel)
  const unsigned short* h1tile = H1 + (size_t)bid*65536 + (size_t)jh*32768
                               + (mt*16 + (lane&15))*64 + (lane>>4)*8;
  for (int jj = 0; jj < 16; jj++){
    int j = jh*16 + jj;
    bfv8 a0 = __builtin_bit_cast(bfv8, *reinterpret_cast<const u32x4v*>(h1tile + jj*2048));
    bfv8 a1 = __builtin_bit_cast(bfv8, *reinterpret_cast<const u32x4v*>(h1tile + jj*2048 + 32));
    #pragma unroll
    for (int nt2 = 0; nt2 < 2; nt2++){
      f32x4 acc = {0.f,0.f,0.f,0.f};
      acc = __builtin_amdgcn_mfma_f32_16x16x32_bf16(a0, bw[nt2][0], acc, 0, 0, 0);
      acc = __builtin_amdgcn_mfma_f32_16x16x32_bf16(a1, bw[nt2][1], acc, 0, 0, 0);
      int dcol = (ntb+nt2)*16 + (lane & 15);
      float rb = RB2[j*64 + dcol];
      float t13j = 0.f;
      #pragma unroll
      for (int r = 0; r < 4; r++){
        int kl = mt*16 + (lane >> 4)*4 + r;   // C/D: col=lane&15, row=(lane>>4)*4+r
        float val = acc[r] + rb + QC2[QIDX(kl,dcol)] + ws[O_P2 + ((b*32+j)*32 + kl)*64 + dcol];
        if (PASS == 0){ ssum[nt2] += val; ssq[nt2] += val*val; }
        else {
          float h2 = fmaxf(val*sc2v[nt2] + sh2v[nt2], 0.f);
          t23a[nt2] += h2; t13j += h2; t12a[nt2][r] += h2;
        }
      }
      if (PASS == 1){
        t13j += __shfl_xor(t13j, 16); t13j += __shfl_xor(t13j, 32);
        if ((lane >> 4) == 0) atomicAdd(&ws[O_T13 + (b*32+j)*64 + dcol], t13j);
      }
    }
  }
  if (PASS == 0){
    #pragma unroll
    for (int nt2 = 0; nt2 < 2; nt2++){
      float v = ssum[nt2]; v += __shfl_xor(v,16); v += __shfl_xor(v,32);
      float q = ssq[nt2];  q += __shfl_xor(q,16); q += __shfl_xor(q,32);
      if (lane < 16){ redA[(w*2+nt2)*16 + lane] = v; redB[(w*2+nt2)*16 + lane] = q; }
    }
    __syncthreads();
    if (t < 64){
      int nt = t >> 4, d15 = t & 15, w0 = (nt >> 1)*2, n2 = nt & 1;
      atomicAdd(&ws[O_SUM2 + t], redA[(w0*2+n2)*16+d15] + redA[((w0+1)*2+n2)*16+d15]);
      atomicAdd(&ws[O_SSQ2 + t], redB[(w0*2+n2)*16+d15] + redB[((w0+1)*2+n2)*16+d15]);
    }
  } else {
    #pragma unroll
    for (int nt2 = 0; nt2 < 2; nt2++){
      float v = t23a[nt2]; v += __shfl_xor(v,16); v += __shfl_xor(v,32);
      if (lane < 16) redA[(w*2+nt2)*16 + lane] = v;
    }
    __syncthreads();
    if (t < 64){
      int nt = t >> 4, d15 = t & 15, w0 = (nt >> 1)*2, n2 = nt & 1;
      atomicAdd(&ws[O_T23 + bid*64 + t], redA[(w0*2+n2)*16+d15] + redA[((w0+1)*2+n2)*16+d15]);
    }
    #pragma unroll
    for (int nt2 = 0; nt2 < 2; nt2++){
      int dcol = (ntb+nt2)*16 + (lane & 15);
      #pragma unroll
      for (int r = 0; r < 4; r++){
        int kl = mt*16 + (lane >> 4)*4 + r;
        atomicAdd(&ws[O_T12 + (b*32+kl)*64 + dcol], t12a[nt2][r]);
      }
    }
  }
}

// ---------------- final head ----------------
__global__ __launch_bounds__(64) void k_final_d3(const float* __restrict__ Wc, float* __restrict__ ws){
  int b = blockIdx.x; int t = threadIdx.x;
  __shared__ float l[64];
  float a = 0.f;
  for (int m = 0; m < 32; m++) a += ws[O_T23 + (b*32+m)*64 + t];
  l[t] = a * (1.f/32768.f);
  __syncthreads();
  float dv = 0.f;
  for (int c = 0; c < 64; c++) dv += l[c] * Wc[(192 + c)*64 + t];
  ws[O_D3 + b*64 + t] = dv;
}

__global__ __launch_bounds__(64) void k_final_out1(const float* __restrict__ Wc, float* __restrict__ ws){
  int bid = blockIdx.x; int b = bid >> 5; int t = threadIdx.x;
  __shared__ float r23[64], r13[64], r12[64];
  r23[t] = ws[O_T23 + bid*64+t] * (1.f/1024.f);
  r13[t] = ws[O_T13 + bid*64+t] * (1.f/1024.f);
  r12[t] = ws[O_T12 + bid*64+t] * (1.f/1024.f);
  __syncthreads();
  float o = ws[O_D3 + b*64 + t];
  for (int c = 0; c < 64; c++){
    o += r23[c]*Wc[c*64+t] + r13[c]*Wc[(64+c)*64+t] + r12[c]*Wc[(128+c)*64+t];
  }
  ws[O_OUT1 + bid*64+t] = o;
  atomicAdd(&ws[O_SUMC + t], o);
  atomicAdd(&ws[O_SSQC + t], o*o);
}

__global__ __launch_bounds__(64) void k_final_bn(const float* __restrict__ gc, const float* __restrict__ bc,
                                                 const float* __restrict__ ws, float* __restrict__ out){
  int bid = blockIdx.x; int t = threadIdx.x;
  float mu = ws[O_SUMC+t] * (1.f/512.f);
  float var = ws[O_SSQC+t] * (1.f/512.f) - mu*mu;
  float rs = rsqrtf(var + 1e-5f);
  out[bid*64 + t] = (ws[O_OUT1 + bid*64+t] - mu) * rs * gc[t] + bc[t];
}

extern "C" void kernel_launch(void* const* d_in, const int* in_sizes, int n_in,
                              void* d_out, int out_size, void* d_ws, size_t ws_size,
                              hipStream_t stream) {
  const float* x   = (const float*)d_in[0];
  const float* xn  = (const float*)d_in[1];
  const float* W1  = (const float*)d_in[2];
  const float* Wn1 = (const float*)d_in[3];
  const float* g1  = (const float*)d_in[4];
  const float* b1  = (const float*)d_in[5];
  const float* W2  = (const float*)d_in[6];
  const float* g2  = (const float*)d_in[7];
  const float* b2p = (const float*)d_in[8];
  const float* Wc  = (const float*)d_in[9];
  const float* gc  = (const float*)d_in[10];
  const float* bc  = (const float*)d_in[11];
  float* out = (float*)d_out;
  float* ws  = (float*)d_ws;
  unsigned short* H1 = (unsigned short*)(ws + O_H1);
  (void)in_sizes; (void)n_in; (void)out_size; (void)ws_size; // needs ws_size >= ~107MB

  // zero atomic accumulation targets
  hipMemsetAsync(ws + O_SUM1, 0, 128*4, stream);
  hipMemsetAsync(ws + O_SUM2, 0, 128*4, stream);
  hipMemsetAsync(ws + O_SUMC, 0, 128*4, stream);
  hipMemsetAsync(ws + O_T23,  0, 98304*4, stream);   // T23 + T13 + T12 contiguous
  hipMemsetAsync(ws + O_BN1P, 0, 7168*4, stream);

  k_means   <<<16,    512, 0, stream>>>(x, ws);
  k_wcomb   <<<1,     64,  0, stream>>>(W1, ws);
  k_pairs1  <<<16384, 64,  0, stream>>>(x, ws);
  k_singles1<<<512,   64,  0, stream>>>(xn, Wn1, ws);
  k_bn1a    <<<128,   256, 0, stream>>>(ws);
  k_bn1b    <<<16,    64,  0, stream>>>(ws);
  k_bnfin   <<<1,     64,  0, stream>>>(g1, b1, ws, O_SUM1, O_SSQ1, O_SC1, O_SH1, 1.f/524288.f);
  k_sweep1  <<<512,   256, 0, stream>>>(ws, H1);
  k_hred    <<<512,   256, 0, stream>>>(ws, H1);
  k_pairs2  <<<16384, 64,  0, stream>>>(W2, ws);
  k_sred    <<<512,   64,  0, stream>>>(ws);
  k_d2      <<<16,    64,  0, stream>>>(W2, ws);
  k_ss2     <<<512,   64,  0, stream>>>(W2, ws);
  k_y2lean<0><<<1024, 256, 0, stream>>>(W2, ws, H1);
  k_bnfin   <<<1,     64,  0, stream>>>(g2, b2p, ws, O_SUM2, O_SSQ2, O_SC2, O_SH2, 1.f/524288.f);
  k_y2lean<1><<<1024, 256, 0, stream>>>(W2, ws, H1);
  k_final_d3<<<16,    64,  0, stream>>>(Wc, ws);
  k_final_out1<<<512, 64,  0, stream>>>(Wc, ws);
  k_final_bn<<<512,   64,  0, stream>>>(gc, bc, ws, out);
}